// Round 10
// baseline (325.146 us; speedup 1.0000x reference)
//
#include <hip/hip_runtime.h>

typedef unsigned short u16;
typedef unsigned int u32;
typedef short bf16x8 __attribute__((ext_vector_type(8)));
typedef float f32x4 __attribute__((ext_vector_type(4)));

#define DEV static __device__ __forceinline__

constexpr float LN_EPS = 1e-5f;
constexpr float SCALE = 0.0625f; // 256^-0.5

DEV float bf2f(u32 u) { return __uint_as_float(u << 16); }
DEV float bfe(short x) { return __uint_as_float(((u32)(u16)x) << 16); }
DEV u16 f2bf(float f) {
  u32 u = __float_as_uint(f);
  return (u16)((u + 0x7fffu + ((u >> 16) & 1u)) >> 16);
}
DEV u32 pk2(float a, float b) { return (u32)f2bf(a) | ((u32)f2bf(b) << 16); }

// ---------------- K0: convert weights to bf16 ----------------
__global__ __launch_bounds__(256) void k_convert(
    const float* __restrict__ Wk, const float* __restrict__ Wv,
    const float* __restrict__ Wih, const float* __restrict__ Whh,
    const float* __restrict__ W1, const float* __restrict__ W2,
    const float* __restrict__ Wq,
    u16* __restrict__ wkvT, u16* __restrict__ wih_f, u16* __restrict__ whh_f,
    u16* __restrict__ w1_f, u16* __restrict__ w2_f, u16* __restrict__ wq_f,
    u16* __restrict__ wqt) {
  int idx = blockIdx.x * 256 + threadIdx.x;
  if (idx < 131072) {                       // wkvT[n][k] = W(k,n)
    int n = idx >> 8, k = idx & 255;
    float v = (n < 256) ? Wk[k * 256 + n] : Wv[k * 256 + (n - 256)];
    wkvT[idx] = f2bf(v);
    return;
  }
  idx -= 131072;
  if (idx < 196608) {                       // wih_f
    int j = idx & 7, lane = (idx >> 3) & 63, tile = idx >> 9;
    int kt = tile & 7, nt = tile >> 3;
    int k = kt * 32 + ((lane >> 4) << 3) + j, n = nt * 16 + (lane & 15);
    wih_f[idx] = f2bf(Wih[k * 768 + n]);
    return;
  }
  idx -= 196608;
  if (idx < 196608) {                       // whh_f
    int j = idx & 7, lane = (idx >> 3) & 63, tile = idx >> 9;
    int kt = tile & 7, nt = tile >> 3;
    int k = kt * 32 + ((lane >> 4) << 3) + j, n = nt * 16 + (lane & 15);
    whh_f[idx] = f2bf(Whh[k * 768 + n]);
    return;
  }
  idx -= 196608;
  if (idx < 131072) {                       // w1_f
    int j = idx & 7, lane = (idx >> 3) & 63, tile = idx >> 9;
    int kt = tile & 7, nt = tile >> 3;
    int k = kt * 32 + ((lane >> 4) << 3) + j, n = nt * 16 + (lane & 15);
    w1_f[idx] = f2bf(W1[k * 512 + n]);
    return;
  }
  idx -= 131072;
  if (idx < 131072) {                       // w2_f (KT=16)
    int j = idx & 7, lane = (idx >> 3) & 63, tile = idx >> 9;
    int kt = tile & 15, nt = tile >> 4;
    int k = kt * 32 + ((lane >> 4) << 3) + j, n = nt * 16 + (lane & 15);
    w2_f[idx] = f2bf(W2[k * 256 + n]);
    return;
  }
  idx -= 131072;
  if (idx < 65536) {                        // wq_f
    int j = idx & 7, lane = (idx >> 3) & 63, tile = idx >> 9;
    int kt = tile & 7, nt = tile >> 3;
    int k = kt * 32 + ((lane >> 4) << 3) + j, n = nt * 16 + (lane & 15);
    wq_f[idx] = f2bf(Wq[k * 256 + n]);
    return;
  }
  idx -= 65536;
  if (idx < 65536) {                        // wqt[t][d] = Wq[d][t]
    int t = idx >> 8, d = idx & 255;
    wqt[idx] = f2bf(Wq[d * 256 + t]);
    return;
  }
}

// ---------------- K2: slots init + first q ----------------
__global__ __launch_bounds__(256) void k_slots_init(
    const float* __restrict__ noise, const float* __restrict__ mu,
    const float* __restrict__ sig, const float* __restrict__ g,
    const float* __restrict__ b, const u16* __restrict__ wqt,
    float* __restrict__ slots, float* __restrict__ qbuf) {
  int bs = blockIdx.x, t = threadIdx.x;
  float sg = sig[t];
  float sp = (sg > 20.f) ? sg : log1pf(expf(sg));
  sp = fminf(fmaxf(sp, 0.1f), 2.0f);
  float sl = mu[t] + sp * noise[bs * 256 + t];
  slots[bs * 256 + t] = sl;
  __shared__ float red[8];
  __shared__ __align__(16) float sln[256];
  float s = sl, ss = sl * sl;
#pragma unroll
  for (int o = 32; o; o >>= 1) { s += __shfl_xor(s, o); ss += __shfl_xor(ss, o); }
  int w = t >> 6;
  if ((t & 63) == 0) { red[w] = s; red[4 + w] = ss; }
  __syncthreads();
  s = red[0] + red[1] + red[2] + red[3];
  ss = red[4] + red[5] + red[6] + red[7];
  float mean = s * (1.f / 256.f);
  float rstd = rsqrtf(ss * (1.f / 256.f) - mean * mean + LN_EPS);
  sln[t] = (sl - mean) * rstd * g[t] + b[t];
  __syncthreads();
  float acc = 0.f;
  const bf16x8* wqp = (const bf16x8*)(wqt + t * 256);
#pragma unroll 4
  for (int db = 0; db < 32; ++db) {
    float q8[8];
    *(float4*)q8 = *(const float4*)&sln[db * 8];
    *(float4*)(q8 + 4) = *(const float4*)&sln[db * 8 + 4];
    bf16x8 wv = wqp[db];
#pragma unroll
    for (int j = 0; j < 8; ++j) acc += q8[j] * bfe(wv[j]);
  }
  qbuf[bs * 256 + t] = acc;
}

// ---------------- KG: fused LN + kv GEMM, 64-row tiles, all nt in-block ----------------
// LDS: A [0,32768)B 64x256 bf16 swizzled; B [32768,49152)B staging; bounce [49152,66560)B
__global__ __launch_bounds__(256) void k_lngemm(
    const float* __restrict__ inF, const float* __restrict__ lng,
    const float* __restrict__ lnb, const u16* __restrict__ Wt,
    u16* __restrict__ kT, u16* __restrict__ vT) {
  __shared__ __align__(16) u16 smem[33280];   // 66560 bytes
  int mt = (blockIdx.x & 7) * 256 + (blockIdx.x >> 3);   // XCD swizzle, 2048 blocks
  int grow = mt * 64;
  int bb = grow >> 12, nb0 = grow & 4095;
  int t = threadIdx.x, w = t >> 6, lane = t & 63;
  u16* Bbase = smem + 16384;          // byte 32768
  char* bounce = (char*)smem + 49152;
  float* redp = (float*)bounce;       // [64][8] f32 partials (2 KB)

  // issue B stage (nt=0, ks=0) first so it overlaps the LN phase
  {
#pragma unroll
    for (int i = 0; i < 4; ++i) {
      int cbase = (w * 4 + i) * 64;
      int c = cbase + lane;
      int r = c >> 3, sc = c & 7;
      const u16* srcB = Wt + r * 256 + ((sc ^ (r & 7)) << 3);
      __builtin_amdgcn_global_load_lds(
          (const __attribute__((address_space(1))) void*)srcB,
          (__attribute__((address_space(3))) void*)(Bbase + cbase * 8), 16, 0, 0);
    }
  }
  // ---- LN phase: thread t -> row r = t>>2, quarter q = t&3 (64 elems) ----
  float4 vv[16];
  {
    int r = t >> 2, q = t & 3;
    const float4* src = (const float4*)(inF + (size_t)(grow + r) * 256 + q * 64);
    float s = 0.f, ss = 0.f;
#pragma unroll
    for (int i = 0; i < 16; ++i) {
      vv[i] = src[i];
      s += vv[i].x + vv[i].y + vv[i].z + vv[i].w;
      ss += vv[i].x * vv[i].x + vv[i].y * vv[i].y + vv[i].z * vv[i].z + vv[i].w * vv[i].w;
    }
    redp[r * 8 + q] = s;
    redp[r * 8 + 4 + q] = ss;
  }
  __syncthreads();
  {
    int r = t >> 2, q = t & 3;
    float s = redp[r * 8] + redp[r * 8 + 1] + redp[r * 8 + 2] + redp[r * 8 + 3];
    float ss = redp[r * 8 + 4] + redp[r * 8 + 5] + redp[r * 8 + 6] + redp[r * 8 + 7];
    float mean = s * (1.f / 256.f);
    float rstd = rsqrtf(ss * (1.f / 256.f) - mean * mean + LN_EPS);
    const float4* gp = (const float4*)(lng + q * 64);
    const float4* bp = (const float4*)(lnb + q * 64);
#pragma unroll
    for (int j = 0; j < 8; ++j) {
      float4 a = vv[2 * j], bfl = vv[2 * j + 1];
      float4 gv0 = gp[2 * j], gv1 = gp[2 * j + 1];
      float4 bv0 = bp[2 * j], bv1 = bp[2 * j + 1];
      uint4 pk;
      pk.x = pk2((a.x - mean) * rstd * gv0.x + bv0.x, (a.y - mean) * rstd * gv0.y + bv0.y);
      pk.y = pk2((a.z - mean) * rstd * gv0.z + bv0.z, (a.w - mean) * rstd * gv0.w + bv0.w);
      pk.z = pk2((bfl.x - mean) * rstd * gv1.x + bv1.x, (bfl.y - mean) * rstd * gv1.y + bv1.y);
      pk.w = pk2((bfl.z - mean) * rstd * gv1.z + bv1.z, (bfl.w - mean) * rstd * gv1.w + bv1.w);
      int cc = q * 8 + j;
      *(uint4*)((char*)smem + r * 512 + ((cc ^ (r & 7)) << 4)) = pk;
    }
  }
  // ---- GEMM: loop nt, K-steps with single-buffer B prefetch ----
  f32x4 acc[8] = {};
  for (int nt = 0; nt < 4; ++nt) {
    for (int ks = 0; ks < 4; ++ks) {
      __syncthreads();            // B(cur) landed + (first iter) A ready
#pragma unroll
      for (int kk = 0; kk < 2; ++kk) {
        int lrow = w * 16 + (lane & 15);
        int cc = ks * 8 + kk * 4 + (lane >> 4);
        bf16x8 af = *(const bf16x8*)((const char*)smem + lrow * 512 + ((cc ^ (lrow & 7)) << 4));
#pragma unroll
        for (int n = 0; n < 8; ++n) {
          int lcol = n * 16 + (lane & 15);
          int slot = (kk * 4 + (lane >> 4)) ^ (lcol & 7);
          bf16x8 bfr = *(const bf16x8*)((const char*)smem + 32768 + lcol * 128 + slot * 16);
          acc[n] = __builtin_amdgcn_mfma_f32_16x16x32_bf16(af, bfr, acc[n], 0, 0, 0);
        }
      }
      __syncthreads();            // all waves done reading B(cur)
      int nks = ks + 1, nnt = nt;
      if (nks == 4) { nks = 0; nnt = nt + 1; }
      if (nnt < 4) {
#pragma unroll
        for (int i = 0; i < 4; ++i) {
          int cbase = (w * 4 + i) * 64;
          int c = cbase + lane;
          int r = c >> 3, sc = c & 7;
          const u16* srcB = Wt + (nnt * 128 + r) * 256 + nks * 64 + ((sc ^ (r & 7)) << 3);
          __builtin_amdgcn_global_load_lds(
              (const __attribute__((address_space(1))) void*)srcB,
              (__attribute__((address_space(3))) void*)(Bbase + cbase * 8), 16, 0, 0);
        }
      }
    }
    // ---- epilogue nt: bounce [col 128][row 64] stride 136B, then d-major store ----
#pragma unroll
    for (int n = 0; n < 8; ++n) {
      int col = n * 16 + (lane & 15);
      int r0 = w * 16 + (lane >> 4) * 4;
      uint2 pk;
      pk.x = pk2(acc[n][0], acc[n][1]);
      pk.y = pk2(acc[n][2], acc[n][3]);
      *(uint2*)(bounce + col * 136 + r0 * 2) = pk;
      acc[n] = (f32x4){0.f, 0.f, 0.f, 0.f};
    }
    __syncthreads();
    {
      u16* outp = (nt < 2 ? kT : vT) + (size_t)bb * (1 << 20) + (nt & 1) * 128 * 4096 + nb0;
      int d = t >> 1, seg = t & 1;
#pragma unroll
      for (int i = 0; i < 16; ++i) {
        u32 val = *(const u32*)(bounce + d * 136 + seg * 64 + i * 4);
        *(u32*)(outp + (size_t)d * 4096 + seg * 32 + i * 2) = val;
      }
    }
    __syncthreads();
  }
}

// ---------------- K3: QK^T per (b, chunk): pml + chunk-local p (bf16, transposed) ----------------
__global__ __launch_bounds__(128) void k_dots(
    const u16* __restrict__ kT, const float* __restrict__ qbuf,
    float* __restrict__ pml, u16* __restrict__ plT) {
  int bid = (blockIdx.x & 7) * 64 + (blockIdx.x >> 3);
  int b = bid >> 4, c = bid & 15;
  int n0 = c * 256;
  int t = threadIdx.x, w = t >> 6, lane = t & 63;
  __shared__ __align__(16) float qT[256][8];
  __shared__ float red[16];
  for (int i = t; i < 2048; i += 128) {
    int s = i >> 8, d = i & 255;
    qT[d][s] = qbuf[(b * 8 + s) * 256 + d];
  }
  __syncthreads();
  float acc[8][2] = {};
  const u16* kp = kT + (size_t)b * (1 << 20) + n0 + 2 * t;
#pragma unroll 8
  for (int d = 0; d < 256; ++d) {
    u32 kk = *(const u32*)(kp + (size_t)d * 4096);
    float k0 = bf2f(kk & 0xffffu), k1 = bf2f(kk >> 16);
    float q8[8];
    *(float4*)q8 = *(const float4*)&qT[d][0];
    *(float4*)(q8 + 4) = *(const float4*)&qT[d][4];
#pragma unroll
    for (int s = 0; s < 8; ++s) { acc[s][0] += k0 * q8[s]; acc[s][1] += k1 * q8[s]; }
  }
  float mx[8];
#pragma unroll
  for (int s = 0; s < 8; ++s) {
    acc[s][0] *= SCALE; acc[s][1] *= SCALE;
    float lm = fmaxf(acc[s][0], acc[s][1]);
#pragma unroll
    for (int o = 32; o; o >>= 1) lm = fmaxf(lm, __shfl_xor(lm, o));
    if (lane == 0) red[w * 8 + s] = lm;
  }
  __syncthreads();
#pragma unroll
  for (int s = 0; s < 8; ++s) mx[s] = fmaxf(red[s], red[8 + s]);
  __syncthreads();
  float pv0[8], pv1[8];
#pragma unroll
  for (int s = 0; s < 8; ++s) {
    pv0[s] = __expf(acc[s][0] - mx[s]);
    pv1[s] = __expf(acc[s][1] - mx[s]);
    float l = pv0[s] + pv1[s];
#pragma unroll
    for (int o = 32; o; o >>= 1) l += __shfl_xor(l, o);
    if (lane == 0) red[w * 8 + s] = l;
  }
  __syncthreads();
  if (t < 8) {
    pml[(b * 16 + c) * 16 + t] = mx[t];
    pml[(b * 16 + c) * 16 + 8 + t] = red[t] + red[8 + t];
  }
  u16* pp = plT + (size_t)b * 65536 + n0 + 2 * t;
#pragma unroll
  for (int s = 0; s < 8; ++s) {
    *(u32*)(pp + s * 4096) = pk2(pv0[s], pv1[s]);
    *(u32*)(pp + (8 + s) * 4096) = 0u;
  }
}

// ---------------- K4: PV GEMM with flash rescale; writes ufrag directly ----------------
__global__ __launch_bounds__(256) void k_pv(
    const u16* __restrict__ plT, const u16* __restrict__ vT,
    const float* __restrict__ pml, u16* __restrict__ ufrag) {
  int bid = (blockIdx.x & 7) * 64 + (blockIdx.x >> 3);
  int b = bid >> 4, nt = bid & 15;
  int w = threadIdx.x >> 6, lane = threadIdx.x & 63;
  int r0 = (lane >> 4) * 4;
  float wcv[4][4];
  const float* pb = pml + b * 256;
#pragma unroll
  for (int j = 0; j < 4; ++j) {
    int s = r0 + j;
    if (s < 8) {
      float M = -1e30f;
#pragma unroll
      for (int c = 0; c < 16; ++c) M = fmaxf(M, pb[c * 16 + s]);
      float L = 0.f;
#pragma unroll
      for (int c = 0; c < 16; ++c) L += pb[c * 16 + 8 + s] * __expf(pb[c * 16 + s] - M);
      float invL = 1.f / L;
#pragma unroll
      for (int cc = 0; cc < 4; ++cc)
        wcv[cc][j] = __expf(pb[(w * 4 + cc) * 16 + s] - M) * invL;
    } else {
#pragma unroll
      for (int cc = 0; cc < 4; ++cc) wcv[cc][j] = 0.f;
    }
  }
  const u16* pA = plT + (size_t)b * 65536 + (lane & 15) * 4096 + ((lane >> 4) << 3);
  const u16* pB = vT + (size_t)b * (1 << 20) + (size_t)(nt * 16 + (lane & 15)) * 4096 + ((lane >> 4) << 3);
  f32x4 tot = {};
#pragma unroll
  for (int cc = 0; cc < 4; ++cc) {
    f32x4 acc = {};
    int kbase = (w * 4 + cc) * 256;
#pragma unroll
    for (int q = 0; q < 8; ++q) {
      int n = kbase + q * 32;
      bf16x8 a = *(const bf16x8*)(pA + n);
      bf16x8 bb = *(const bf16x8*)(pB + n);
      acc = __builtin_amdgcn_mfma_f32_16x16x32_bf16(a, bb, acc, 0, 0, 0);
    }
#pragma unroll
    for (int j = 0; j < 4; ++j) tot[j] += wcv[cc][j] * acc[j];
  }
  __shared__ __align__(16) float red[4][64][4];
  *(float4*)&red[w][lane][0] = *(float4*)&tot;
  __syncthreads();
  if (w == 0 && r0 < 8) {
    float4 t0 = *(float4*)&red[0][lane][0];
    float4 t1 = *(float4*)&red[1][lane][0];
    float4 t2 = *(float4*)&red[2][lane][0];
    float4 t3 = *(float4*)&red[3][lane][0];
    float rr[4] = {t0.x + t1.x + t2.x + t3.x, t0.y + t1.y + t2.y + t3.y,
                   t0.z + t1.z + t2.z + t3.z, t0.w + t1.w + t2.w + t3.w};
    int d = nt * 16 + (lane & 15);
    int mt = b >> 1, kt = d >> 5;
    int laneBase = ((d >> 3) & 3) * 16;
#pragma unroll
    for (int j = 0; j < 4; ++j) {
      int row16 = (b & 1) * 8 + r0 + j;
      ufrag[((mt * 8 + kt) * 64 + laneBase + row16) * 8 + (d & 7)] = f2bf(rr[j]);
    }
  }
}

// ---------------- U1: gates GEMM + GRU elementwise -> snew (h staged in LDS) ----------------
__global__ __launch_bounds__(256) void k_gru2(
    const u16* __restrict__ ufrag, const float* __restrict__ slots_in,
    const u16* __restrict__ wih_f, const u16* __restrict__ whh_f,
    const float* __restrict__ bih, const float* __restrict__ bhh,
    float* __restrict__ snew) {
  __shared__ __align__(16) u16 hfl[4096];
  int bid = blockIdx.x;
  int mt = bid >> 2;
  int t = threadIdx.x, w = t >> 6, lane = t & 63;
  {
    int r16 = t >> 4, cg = t & 15;
    int row = mt * 16 + r16;
    int kt = cg >> 1;
    int laneLo = (cg & 1) * 32 + r16;
    int laneHi = laneLo + 16;
    const float4* hp = (const float4*)(slots_in + (size_t)row * 256 + cg * 16);
    float4 h0 = hp[0], h1 = hp[1], h2 = hp[2], h3 = hp[3];
    uint4 pk;
    pk.x = pk2(h0.x, h0.y); pk.y = pk2(h0.z, h0.w);
    pk.z = pk2(h1.x, h1.y); pk.w = pk2(h1.z, h1.w);
    *(uint4*)(hfl + (kt * 64 + laneLo) * 8) = pk;
    pk.x = pk2(h2.x, h2.y); pk.y = pk2(h2.z, h2.w);
    pk.z = pk2(h3.x, h3.y); pk.w = pk2(h3.z, h3.w);
    *(uint4*)(hfl + (kt * 64 + laneHi) * 8) = pk;
  }
  __syncthreads();
  int g = (bid & 3) * 4 + w;
  const bf16x8* wih = (const bf16x8*)wih_f;
  const bf16x8* whh = (const bf16x8*)whh_f;
  f32x4 ar = {}, az = {}, an = {}, hr = {}, hz = {}, hn = {};
#pragma unroll
  for (int kt = 0; kt < 8; ++kt) {
    bf16x8 au = *(const bf16x8*)(ufrag + ((mt * 8 + kt) * 64 + lane) * 8);
    bf16x8 ah = *(const bf16x8*)(hfl + (kt * 64 + lane) * 8);
    ar = __builtin_amdgcn_mfma_f32_16x16x32_bf16(au, wih[(g * 8 + kt) * 64 + lane], ar, 0, 0, 0);
    az = __builtin_amdgcn_mfma_f32_16x16x32_bf16(au, wih[((16 + g) * 8 + kt) * 64 + lane], az, 0, 0, 0);
    an = __builtin_amdgcn_mfma_f32_16x16x32_bf16(au, wih[((32 + g) * 8 + kt) * 64 + lane], an, 0, 0, 0);
    hr = __builtin_amdgcn_mfma_f32_16x16x32_bf16(ah, whh[(g * 8 + kt) * 64 + lane], hr, 0, 0, 0);
    hz = __builtin_amdgcn_mfma_f32_16x16x32_bf16(ah, whh[((16 + g) * 8 + kt) * 64 + lane], hz, 0, 0, 0);
    hn = __builtin_amdgcn_mfma_f32_16x16x32_bf16(ah, whh[((32 + g) * 8 + kt) * 64 + lane], hn, 0, 0, 0);
  }
  int tc = g * 16 + (lane & 15);
  float cr = bih[tc], cz = bih[256 + tc], cn = bih[512 + tc];
  float dr = bhh[tc], dz = bhh[256 + tc], dn = bhh[512 + tc];
#pragma unroll
  for (int j = 0; j < 4; ++j) {
    int row = mt * 16 + (lane >> 4) * 4 + j;
    float r = 1.f / (1.f + __expf(-(ar[j] + cr + hr[j] + dr)));
    float z = 1.f / (1.f + __expf(-(az[j] + cz + hz[j] + dz)));
    float ng = tanhf(an[j] + cn + r * (hn[j] + dn));
    float h = slots_in[row * 256 + tc];
    snew[row * 256 + tc] = (1.f - z) * ng + z * h;
  }
}

// ---------------- U2: LN(snew) inline + MLP1 -> h1 frags ----------------
__global__ __launch_bounds__(256) void k_mlp1ln(
    const float* __restrict__ sn, const float* __restrict__ gm,
    const float* __restrict__ bm, const u16* __restrict__ w1_f,
    const float* __restrict__ b1v, u16* __restrict__ h1frag) {
  __shared__ __align__(16) u16 afr[4096];
  int w = threadIdx.x >> 6, lane = threadIdx.x & 63;
  int mt = blockIdx.x >> 3;
  int d0 = lane * 4;
  float4 gvv = *(const float4*)(gm + d0);
  float4 bvv = *(const float4*)(bm + d0);
#pragma unroll
  for (int i = 0; i < 4; ++i) {
    int r16 = w * 4 + i;
    float4 v = *(const float4*)(sn + (mt * 16 + r16) * 256 + d0);
    float s = v.x + v.y + v.z + v.w;
    float ss = v.x * v.x + v.y * v.y + v.z * v.z + v.w * v.w;
#pragma unroll
    for (int o = 32; o; o >>= 1) { s += __shfl_xor(s, o); ss += __shfl_xor(ss, o); }
    float mean = s * (1.f / 256.f);
    float rstd = rsqrtf(ss * (1.f / 256.f) - mean * mean + LN_EPS);
    uint2 pk;
    pk.x = pk2((v.x - mean) * rstd * gvv.x + bvv.x, (v.y - mean) * rstd * gvv.y + bvv.y);
    pk.y = pk2((v.z - mean) * rstd * gvv.z + bvv.z, (v.w - mean) * rstd * gvv.w + bvv.w);
    int kt = lane >> 3;
    int laneA = ((lane >> 1) & 3) * 16 + r16;
    *(uint2*)(afr + (kt * 64 + laneA) * 8 + (lane & 1) * 4) = pk;
  }
  __syncthreads();
  int nt = (blockIdx.x & 7) * 4 + w;
  const bf16x8* bw = (const bf16x8*)w1_f;
  f32x4 acc = {};
#pragma unroll
  for (int kt = 0; kt < 8; ++kt)
    acc = __builtin_amdgcn_mfma_f32_16x16x32_bf16(
        *(const bf16x8*)(afr + (kt * 64 + lane) * 8),
        bw[(nt * 8 + kt) * 64 + lane], acc, 0, 0, 0);
  int col = nt * 16 + (lane & 15);
  float bbv = b1v[col];
  int kt2 = col >> 5, j2 = col & 7;
  int laneBase = ((col >> 3) & 3) * 16;
#pragma unroll
  for (int j = 0; j < 4; ++j) {
    int r = (lane >> 4) * 4 + j;
    float vv = fmaxf(acc[j] + bbv, 0.f);
    h1frag[((mt * 16 + kt2) * 64 + laneBase + r) * 8 + j2] = f2bf(vv);
  }
}

// ---------------- U3: MLP2 (h1@W2+b2) + residual -> sout ----------------
__global__ __launch_bounds__(256) void k_mlp2(
    const u16* __restrict__ h1frag, const u16* __restrict__ w2_f,
    const float* __restrict__ b2v, const float* __restrict__ snew,
    float* __restrict__ sout) {
  int w = threadIdx.x >> 6, lane = threadIdx.x & 63;
  int unit = blockIdx.x * 4 + w;       // 0..255
  int mt = unit >> 4, nt = unit & 15;
  const bf16x8* bw = (const bf16x8*)w2_f;
  f32x4 acc = {};
#pragma unroll
  for (int kt = 0; kt < 16; ++kt)
    acc = __builtin_amdgcn_mfma_f32_16x16x32_bf16(
        *(const bf16x8*)(h1frag + ((mt * 16 + kt) * 64 + lane) * 8),
        bw[(nt * 16 + kt) * 64 + lane], acc, 0, 0, 0);
  int col = nt * 16 + (lane & 15);
  float bbv = b2v[col];
#pragma unroll
  for (int j = 0; j < 4; ++j) {
    int row = mt * 16 + (lane >> 4) * 4 + j;
    sout[row * 256 + col] = acc[j] + bbv + snew[row * 256 + col];
  }
}

// ---------------- U4: LN(sout) inline + q GEMM ----------------
__global__ __launch_bounds__(256) void k_qln(
    const float* __restrict__ so, const float* __restrict__ gsv,
    const float* __restrict__ bsv, const u16* __restrict__ wq_f,
    float* __restrict__ qbuf) {
  __shared__ __align__(16) u16 afr[4096];
  int w = threadIdx.x >> 6, lane = threadIdx.x & 63;
  int mt = blockIdx.x >> 2;
  int d0 = lane * 4;
  float4 gvv = *(const float4*)(gsv + d0);
  float4 bvv = *(const float4*)(bsv + d0);
#pragma unroll
  for (int i = 0; i < 4; ++i) {
    int r16 = w * 4 + i;
    float4 v = *(const float4*)(so + (mt * 16 + r16) * 256 + d0);
    float s = v.x + v.y + v.z + v.w;
    float ss = v.x * v.x + v.y * v.y + v.z * v.z + v.w * v.w;
#pragma unroll
    for (int o = 32; o; o >>= 1) { s += __shfl_xor(s, o); ss += __shfl_xor(ss, o); }
    float mean = s * (1.f / 256.f);
    float rstd = rsqrtf(ss * (1.f / 256.f) - mean * mean + LN_EPS);
    uint2 pk;
    pk.x = pk2((v.x - mean) * rstd * gvv.x + bvv.x, (v.y - mean) * rstd * gvv.y + bvv.y);
    pk.y = pk2((v.z - mean) * rstd * gvv.z + bvv.z, (v.w - mean) * rstd * gvv.w + bvv.w);
    int kt = lane >> 3;
    int laneA = ((lane >> 1) & 3) * 16 + r16;
    *(uint2*)(afr + (kt * 64 + laneA) * 8 + (lane & 1) * 4) = pk;
  }
  __syncthreads();
  int nt = (blockIdx.x & 3) * 4 + w;
  const bf16x8* bw = (const bf16x8*)wq_f;
  f32x4 acc = {};
#pragma unroll
  for (int kt = 0; kt < 8; ++kt)
    acc = __builtin_amdgcn_mfma_f32_16x16x32_bf16(
        *(const bf16x8*)(afr + (kt * 64 + lane) * 8),
        bw[(nt * 8 + kt) * 64 + lane], acc, 0, 0, 0);
  int col = nt * 16 + (lane & 15);
#pragma unroll
  for (int j = 0; j < 4; ++j) {
    int row = mt * 16 + (lane >> 4) * 4 + j;
    qbuf[row * 256 + col] = acc[j];
  }
}

extern "C" void kernel_launch(void* const* d_in, const int* in_sizes, int n_in,
                              void* d_out, int out_size, void* d_ws, size_t ws_size,
                              hipStream_t stream) {
  (void)in_sizes; (void)n_in; (void)out_size; (void)ws_size;
  const float* inputs    = (const float*)d_in[0];
  const float* noise     = (const float*)d_in[1];
  const float* ln_in_g   = (const float*)d_in[2];
  const float* ln_in_b   = (const float*)d_in[3];
  const float* ln_slot_g = (const float*)d_in[4];
  const float* ln_slot_b = (const float*)d_in[5];
  const float* ln_mlp_g  = (const float*)d_in[6];
  const float* ln_mlp_b  = (const float*)d_in[7];
  const float* slot_mu   = (const float*)d_in[8];
  const float* slot_sig  = (const float*)d_in[9];
  const float* Wq        = (const float*)d_in[10];
  const float* Wk        = (const float*)d_in[11];
  const float* Wv        = (const float*)d_in[12];
  const float* W_ih      = (const float*)d_in[13];
  const float* W_hh      = (const float*)d_in[14];
  const float* b_ih      = (const float*)d_in[15];
  const float* b_hh      = (const float*)d_in[16];
  const float* W1        = (const float*)d_in[17];
  const float* b1        = (const float*)d_in[18];
  const float* W2        = (const float*)d_in[19];
  const float* b2        = (const float*)d_in[20];

  char* p = (char*)d_ws;
  auto take = [&](size_t bytes) { char* r = p; p += (bytes + 255) & ~(size_t)255; return r; };
  u16* kT       = (u16*)take((size_t)32 * 256 * 4096 * 2);
  u16* vT       = (u16*)take((size_t)32 * 256 * 4096 * 2);
  u16* plT      = (u16*)take((size_t)32 * 16 * 4096 * 2);
  u16* wkvT     = (u16*)take(131072 * 2);
  u16* wih_f    = (u16*)take(196608 * 2);
  u16* whh_f    = (u16*)take(196608 * 2);
  u16* w1_f     = (u16*)take(131072 * 2);
  u16* w2_f     = (u16*)take(131072 * 2);
  u16* wq_f     = (u16*)take(65536 * 2);
  u16* wqt      = (u16*)take(65536 * 2);
  u16* ufrag    = (u16*)take(65536 * 2);
  u16* h1frag   = (u16*)take(131072 * 2);
  float* snew   = (float*)take(65536 * 4);
  float* slotsA = (float*)take(256 * 256 * 4);
  float* slotsB = (float*)take(256 * 256 * 4);
  float* qbuf   = (float*)take(256 * 256 * 4);
  float* pml    = (float*)take(32 * 16 * 16 * 4);

  k_convert<<<3584, 256, 0, stream>>>(Wk, Wv, W_ih, W_hh, W1, W2, Wq,
                                      wkvT, wih_f, whh_f, w1_f, w2_f, wq_f, wqt);
  k_slots_init<<<256, 256, 0, stream>>>(noise, slot_mu, slot_sig, ln_slot_g, ln_slot_b, wqt, slotsA, qbuf);
  k_lngemm<<<2048, 256, 0, stream>>>(inputs, ln_in_g, ln_in_b, wkvT, kT, vT);

  const float* scur = slotsA;
  for (int it = 0; it < 3; ++it) {
    k_dots<<<512, 128, 0, stream>>>(kT, qbuf, pml, plT);
    k_pv<<<512, 256, 0, stream>>>(plT, vT, pml, ufrag);
    k_gru2<<<64, 256, 0, stream>>>(ufrag, scur, wih_f, whh_f, b_ih, b_hh, snew);
    k_mlp1ln<<<128, 256, 0, stream>>>(snew, ln_mlp_g, ln_mlp_b, w1_f, b1, h1frag);
    float* sout = (it == 2) ? (float*)d_out : ((it == 0) ? slotsB : slotsA);
    k_mlp2<<<64, 256, 0, stream>>>(h1frag, w2_f, b2, snew, sout);
    if (it < 2) k_qln<<<64, 256, 0, stream>>>(sout, ln_slot_g, ln_slot_b, wq_f, qbuf);
    scur = sout;
  }
}

// Round 11
// 260.214 us; speedup vs baseline: 1.2495x; 1.2495x over previous
//
#include <hip/hip_runtime.h>

typedef unsigned short u16;
typedef unsigned int u32;
typedef short bf16x8 __attribute__((ext_vector_type(8)));
typedef float f32x4 __attribute__((ext_vector_type(4)));

#define DEV static __device__ __forceinline__

constexpr float LN_EPS = 1e-5f;
constexpr float SCALE = 0.0625f; // 256^-0.5

DEV float bf2f(u32 u) { return __uint_as_float(u << 16); }
DEV float bfe(short x) { return __uint_as_float(((u32)(u16)x) << 16); }
DEV u16 f2bf(float f) {
  u32 u = __float_as_uint(f);
  return (u16)((u + 0x7fffu + ((u >> 16) & 1u)) >> 16);
}
DEV u32 pk2(float a, float b) { return (u32)f2bf(a) | ((u32)f2bf(b) << 16); }

// ---------------- K0: convert weights to bf16 ----------------
__global__ __launch_bounds__(256) void k_convert(
    const float* __restrict__ Wk, const float* __restrict__ Wv,
    const float* __restrict__ Wih, const float* __restrict__ Whh,
    const float* __restrict__ W1, const float* __restrict__ W2,
    const float* __restrict__ Wq,
    u16* __restrict__ wkvT, u16* __restrict__ wih_f, u16* __restrict__ whh_f,
    u16* __restrict__ w1_f, u16* __restrict__ w2_f, u16* __restrict__ wq_f,
    u16* __restrict__ wqt) {
  int idx = blockIdx.x * 256 + threadIdx.x;
  if (idx < 131072) {                       // wkvT[n][k] = W(k,n)
    int n = idx >> 8, k = idx & 255;
    float v = (n < 256) ? Wk[k * 256 + n] : Wv[k * 256 + (n - 256)];
    wkvT[idx] = f2bf(v);
    return;
  }
  idx -= 131072;
  if (idx < 196608) {                       // wih_f
    int j = idx & 7, lane = (idx >> 3) & 63, tile = idx >> 9;
    int kt = tile & 7, nt = tile >> 3;
    int k = kt * 32 + ((lane >> 4) << 3) + j, n = nt * 16 + (lane & 15);
    wih_f[idx] = f2bf(Wih[k * 768 + n]);
    return;
  }
  idx -= 196608;
  if (idx < 196608) {                       // whh_f
    int j = idx & 7, lane = (idx >> 3) & 63, tile = idx >> 9;
    int kt = tile & 7, nt = tile >> 3;
    int k = kt * 32 + ((lane >> 4) << 3) + j, n = nt * 16 + (lane & 15);
    whh_f[idx] = f2bf(Whh[k * 768 + n]);
    return;
  }
  idx -= 196608;
  if (idx < 131072) {                       // w1_f
    int j = idx & 7, lane = (idx >> 3) & 63, tile = idx >> 9;
    int kt = tile & 7, nt = tile >> 3;
    int k = kt * 32 + ((lane >> 4) << 3) + j, n = nt * 16 + (lane & 15);
    w1_f[idx] = f2bf(W1[k * 512 + n]);
    return;
  }
  idx -= 131072;
  if (idx < 131072) {                       // w2_f (KT=16)
    int j = idx & 7, lane = (idx >> 3) & 63, tile = idx >> 9;
    int kt = tile & 15, nt = tile >> 4;
    int k = kt * 32 + ((lane >> 4) << 3) + j, n = nt * 16 + (lane & 15);
    w2_f[idx] = f2bf(W2[k * 256 + n]);
    return;
  }
  idx -= 131072;
  if (idx < 65536) {                        // wq_f
    int j = idx & 7, lane = (idx >> 3) & 63, tile = idx >> 9;
    int kt = tile & 7, nt = tile >> 3;
    int k = kt * 32 + ((lane >> 4) << 3) + j, n = nt * 16 + (lane & 15);
    wq_f[idx] = f2bf(Wq[k * 256 + n]);
    return;
  }
  idx -= 65536;
  if (idx < 65536) {                        // wqt[t][d] = Wq[d][t]
    int t = idx >> 8, d = idx & 255;
    wqt[idx] = f2bf(Wq[d * 256 + t]);
    return;
  }
}

// ---------------- K1: LayerNorm(inputs) -> x bf16 ----------------
__global__ __launch_bounds__(256) void k_ln(const float* __restrict__ in,
    const float* __restrict__ g, const float* __restrict__ b,
    u16* __restrict__ xbf) {
  int row = blockIdx.x * 4 + (threadIdx.x >> 6);
  int lane = threadIdx.x & 63;
  float4 v = ((const float4*)(in + (size_t)row * 256))[lane];
  float s = v.x + v.y + v.z + v.w;
  float ss = v.x * v.x + v.y * v.y + v.z * v.z + v.w * v.w;
#pragma unroll
  for (int o = 32; o; o >>= 1) { s += __shfl_xor(s, o); ss += __shfl_xor(ss, o); }
  float mean = s * (1.f / 256.f);
  float rstd = rsqrtf(ss * (1.f / 256.f) - mean * mean + LN_EPS);
  float4 gv = ((const float4*)g)[lane];
  float4 bv = ((const float4*)b)[lane];
  uint2 o;
  o.x = pk2((v.x - mean) * rstd * gv.x + bv.x, (v.y - mean) * rstd * gv.y + bv.y);
  o.y = pk2((v.z - mean) * rstd * gv.z + bv.z, (v.w - mean) * rstd * gv.w + bv.w);
  ((uint2*)(xbf + (size_t)row * 256))[lane] = o;
}

// ---------------- K2: slots init + first q ----------------
__global__ __launch_bounds__(256) void k_slots_init(
    const float* __restrict__ noise, const float* __restrict__ mu,
    const float* __restrict__ sig, const float* __restrict__ g,
    const float* __restrict__ b, const u16* __restrict__ wqt,
    float* __restrict__ slots, float* __restrict__ qbuf) {
  int bs = blockIdx.x, t = threadIdx.x;
  float sg = sig[t];
  float sp = (sg > 20.f) ? sg : log1pf(expf(sg));
  sp = fminf(fmaxf(sp, 0.1f), 2.0f);
  float sl = mu[t] + sp * noise[bs * 256 + t];
  slots[bs * 256 + t] = sl;
  __shared__ float red[8];
  __shared__ __align__(16) float sln[256];
  float s = sl, ss = sl * sl;
#pragma unroll
  for (int o = 32; o; o >>= 1) { s += __shfl_xor(s, o); ss += __shfl_xor(ss, o); }
  int w = t >> 6;
  if ((t & 63) == 0) { red[w] = s; red[4 + w] = ss; }
  __syncthreads();
  s = red[0] + red[1] + red[2] + red[3];
  ss = red[4] + red[5] + red[6] + red[7];
  float mean = s * (1.f / 256.f);
  float rstd = rsqrtf(ss * (1.f / 256.f) - mean * mean + LN_EPS);
  sln[t] = (sl - mean) * rstd * g[t] + b[t];
  __syncthreads();
  float acc = 0.f;
  const bf16x8* wqp = (const bf16x8*)(wqt + t * 256);
#pragma unroll 4
  for (int db = 0; db < 32; ++db) {
    float q8[8];
    *(float4*)q8 = *(const float4*)&sln[db * 8];
    *(float4*)(q8 + 4) = *(const float4*)&sln[db * 8 + 4];
    bf16x8 wv = wqp[db];
#pragma unroll
    for (int j = 0; j < 8; ++j) acc += q8[j] * bfe(wv[j]);
  }
  qbuf[bs * 256 + t] = acc;
}

// ---------------- KG: kv = x @ [Wk|Wv]; BOTH outputs transposed [b][d][n] ----------------
// XCD swizzle: each XCD gets consecutive (mt,nt) pairs -> A tile hits its L2.
__global__ __launch_bounds__(256) void k_gemm(
    const u16* __restrict__ X, const u16* __restrict__ Wt,
    u16* __restrict__ kT, u16* __restrict__ vT) {
  __shared__ u16 smem[16896];
  int bid = (blockIdx.x & 7) * 512 + (blockIdx.x >> 3);
  int mt = bid >> 2, nt = bid & 3;
  int w = threadIdx.x >> 6, lane = threadIdx.x & 63;
  int wr = w >> 1, wc = w & 1;
  f32x4 acc[4][4] = {};
  for (int ks = 0; ks < 4; ++ks) {
#pragma unroll
    for (int i = 0; i < 4; ++i) {
      int cbase = (w * 4 + i) * 64;
      int c = cbase + lane;
      int r = c >> 3;
      int swz = (c & 7) ^ (r & 7);
      const u16* srcA = X + (mt * 128 + r) * 256 + ks * 64 + swz * 8;
      const u16* srcB = Wt + (nt * 128 + r) * 256 + ks * 64 + swz * 8;
      __builtin_amdgcn_global_load_lds(
          (const __attribute__((address_space(1))) void*)srcA,
          (__attribute__((address_space(3))) void*)(smem + cbase * 8), 16, 0, 0);
      __builtin_amdgcn_global_load_lds(
          (const __attribute__((address_space(1))) void*)srcB,
          (__attribute__((address_space(3))) void*)(smem + 8192 + cbase * 8), 16, 0, 0);
    }
    __syncthreads();
#pragma unroll
    for (int kk = 0; kk < 2; ++kk) {
      bf16x8 af[4], bfr[4];
#pragma unroll
      for (int m = 0; m < 4; ++m) {
        int lrow = wr * 64 + m * 16 + (lane & 15);
        int slot = (kk * 4 + (lane >> 4)) ^ (lrow & 7);
        af[m] = *(const bf16x8*)((const char*)smem + lrow * 128 + slot * 16);
      }
#pragma unroll
      for (int n = 0; n < 4; ++n) {
        int lcol = wc * 64 + n * 16 + (lane & 15);
        int slot = (kk * 4 + (lane >> 4)) ^ (lcol & 7);
        bfr[n] = *(const bf16x8*)((const char*)smem + 16384 + lcol * 128 + slot * 16);
      }
#pragma unroll
      for (int m = 0; m < 4; ++m)
#pragma unroll
        for (int n = 0; n < 4; ++n)
          acc[m][n] = __builtin_amdgcn_mfma_f32_16x16x32_bf16(af[m], bfr[n], acc[m][n], 0, 0, 0);
    }
    __syncthreads();
  }
  int bb = (mt * 128) >> 12;
  int nb0 = (mt * 128) & 4095;
  // transpose via LDS bounce -> T[b][d][n]
#pragma unroll
  for (int m = 0; m < 4; ++m)
#pragma unroll
    for (int n = 0; n < 4; ++n) {
      int col = wc * 64 + n * 16 + (lane & 15);
      int r0 = wr * 64 + m * 16 + (lane >> 4) * 4;
      uint2 pk;
      pk.x = pk2(acc[m][n][0], acc[m][n][1]);
      pk.y = pk2(acc[m][n][2], acc[m][n][3]);
      *(uint2*)((char*)smem + col * 264 + r0 * 2) = pk;
    }
  __syncthreads();
  u16* outp = (nt < 2 ? kT : vT) + (size_t)bb * (1 << 20) + (nt & 1) * 128 * 4096 + nb0;
  for (int i = 0; i < 32; ++i) {
    int dl = w * 32 + i;
    u32 val = *(const u32*)((const char*)smem + dl * 264 + lane * 4);
    *(u32*)(outp + dl * 4096 + 2 * lane) = val;
  }
}

// ---------------- K3: QK^T per (b, chunk), 256 thr with d-split for TLP ----------------
__global__ __launch_bounds__(256) void k_dots(
    const u16* __restrict__ kT, const float* __restrict__ qbuf,
    float* __restrict__ pml, u16* __restrict__ plT) {
  int bid = (blockIdx.x & 7) * 64 + (blockIdx.x >> 3);
  int b = bid >> 4, c = bid & 15;
  int n0 = c * 256;
  int t = threadIdx.x, w = t >> 6, lane = t & 63;
  int i = t & 127, dh = t >> 7;      // n-pair index, d-half
  __shared__ __align__(16) float qT[256][8];
  __shared__ __align__(16) float pl[256][8];
  __shared__ __align__(16) float psum[128][8][2];
  __shared__ float red[16];
  for (int ii = t; ii < 2048; ii += 256) {
    int s = ii >> 8, d = ii & 255;
    qT[d][s] = qbuf[(b * 8 + s) * 256 + d];
  }
  __syncthreads();
  float acc[8][2] = {};
  const u16* kp = kT + (size_t)b * (1 << 20) + (size_t)(dh * 128) * 4096 + n0 + 2 * i;
#pragma unroll 8
  for (int dd = 0; dd < 128; ++dd) {
    int d = dh * 128 + dd;
    u32 kk = *(const u32*)(kp + (size_t)dd * 4096);
    float k0 = bf2f(kk & 0xffffu), k1 = bf2f(kk >> 16);
    float q8[8];
    *(float4*)q8 = *(const float4*)&qT[d][0];
    *(float4*)(q8 + 4) = *(const float4*)&qT[d][4];
#pragma unroll
    for (int s = 0; s < 8; ++s) { acc[s][0] += k0 * q8[s]; acc[s][1] += k1 * q8[s]; }
  }
  if (dh == 1) {
#pragma unroll
    for (int s = 0; s < 8; ++s) { psum[i][s][0] = acc[s][0]; psum[i][s][1] = acc[s][1]; }
  }
  __syncthreads();
  float mx[8];
  if (dh == 0) {
#pragma unroll
    for (int s = 0; s < 8; ++s) {
      acc[s][0] = (acc[s][0] + psum[i][s][0]) * SCALE;
      acc[s][1] = (acc[s][1] + psum[i][s][1]) * SCALE;
      float lm = fmaxf(acc[s][0], acc[s][1]);
#pragma unroll
      for (int o = 32; o; o >>= 1) lm = fmaxf(lm, __shfl_xor(lm, o));
      if (lane == 0) red[w * 8 + s] = lm;
    }
  }
  __syncthreads();
  if (dh == 0) {
#pragma unroll
    for (int s = 0; s < 8; ++s) mx[s] = fmaxf(red[s], red[8 + s]);
  }
  __syncthreads();
  float pv0[8], pv1[8];
  if (dh == 0) {
#pragma unroll
    for (int s = 0; s < 8; ++s) {
      pv0[s] = __expf(acc[s][0] - mx[s]);
      pv1[s] = __expf(acc[s][1] - mx[s]);
      pl[2 * i][s] = pv0[s]; pl[2 * i + 1][s] = pv1[s];
      float l = pv0[s] + pv1[s];
#pragma unroll
      for (int o = 32; o; o >>= 1) l += __shfl_xor(l, o);
      if (lane == 0) red[w * 8 + s] = l;
    }
  }
  __syncthreads();
  if (t < 8) {
    pml[(b * 16 + c) * 16 + t] = mx[t];
    pml[(b * 16 + c) * 16 + 8 + t] = red[t] + red[8 + t];
  }
  if (dh == 0) {
    u16* pp = plT + (size_t)b * 65536 + n0 + 2 * i;
#pragma unroll
    for (int s = 0; s < 8; ++s) {
      *(u32*)(pp + s * 4096) = pk2(pv0[s], pv1[s]);
      *(u32*)(pp + (8 + s) * 4096) = 0u;
    }
  }
}

// ---------------- K4: PV GEMM with flash rescale; writes ufrag directly ----------------
__global__ __launch_bounds__(256) void k_pv(
    const u16* __restrict__ plT, const u16* __restrict__ vT,
    const float* __restrict__ pml, u16* __restrict__ ufrag) {
  int bid = (blockIdx.x & 7) * 64 + (blockIdx.x >> 3);
  int b = bid >> 4, nt = bid & 15;
  int w = threadIdx.x >> 6, lane = threadIdx.x & 63;
  int r0 = (lane >> 4) * 4;
  float wcv[4][4];
  const float* pb = pml + b * 256;
#pragma unroll
  for (int j = 0; j < 4; ++j) {
    int s = r0 + j;
    if (s < 8) {
      float M = -1e30f;
#pragma unroll
      for (int c = 0; c < 16; ++c) M = fmaxf(M, pb[c * 16 + s]);
      float L = 0.f;
#pragma unroll
      for (int c = 0; c < 16; ++c) L += pb[c * 16 + 8 + s] * __expf(pb[c * 16 + s] - M);
      float invL = 1.f / L;
#pragma unroll
      for (int cc = 0; cc < 4; ++cc)
        wcv[cc][j] = __expf(pb[(w * 4 + cc) * 16 + s] - M) * invL;
    } else {
#pragma unroll
      for (int cc = 0; cc < 4; ++cc) wcv[cc][j] = 0.f;
    }
  }
  const u16* pA = plT + (size_t)b * 65536 + (lane & 15) * 4096 + ((lane >> 4) << 3);
  const u16* pB = vT + (size_t)b * (1 << 20) + (size_t)(nt * 16 + (lane & 15)) * 4096 + ((lane >> 4) << 3);
  f32x4 tot = {};
#pragma unroll
  for (int cc = 0; cc < 4; ++cc) {
    f32x4 acc = {};
    int kbase = (w * 4 + cc) * 256;
#pragma unroll
    for (int q = 0; q < 8; ++q) {
      int n = kbase + q * 32;
      bf16x8 a = *(const bf16x8*)(pA + n);
      bf16x8 bb = *(const bf16x8*)(pB + n);
      acc = __builtin_amdgcn_mfma_f32_16x16x32_bf16(a, bb, acc, 0, 0, 0);
    }
#pragma unroll
    for (int j = 0; j < 4; ++j) tot[j] += wcv[cc][j] * acc[j];
  }
  __shared__ __align__(16) float red[4][64][4];
  *(float4*)&red[w][lane][0] = *(float4*)&tot;
  __syncthreads();
  if (w == 0 && r0 < 8) {
    float4 t0 = *(float4*)&red[0][lane][0];
    float4 t1 = *(float4*)&red[1][lane][0];
    float4 t2 = *(float4*)&red[2][lane][0];
    float4 t3 = *(float4*)&red[3][lane][0];
    float rr[4] = {t0.x + t1.x + t2.x + t3.x, t0.y + t1.y + t2.y + t3.y,
                   t0.z + t1.z + t2.z + t3.z, t0.w + t1.w + t2.w + t3.w};
    int d = nt * 16 + (lane & 15);
    int mt = b >> 1, kt = d >> 5;
    int laneBase = ((d >> 3) & 3) * 16;
#pragma unroll
    for (int j = 0; j < 4; ++j) {
      int row16 = (b & 1) * 8 + r0 + j;
      ufrag[((mt * 8 + kt) * 64 + laneBase + row16) * 8 + (d & 7)] = f2bf(rr[j]);
    }
  }
}

// ---------------- U1: gates GEMM + GRU elementwise -> snew (h staged in LDS) ----------------
__global__ __launch_bounds__(256) void k_gru2(
    const u16* __restrict__ ufrag, const float* __restrict__ slots_in,
    const u16* __restrict__ wih_f, const u16* __restrict__ whh_f,
    const float* __restrict__ bih, const float* __restrict__ bhh,
    float* __restrict__ snew) {
  __shared__ __align__(16) u16 hfl[4096];
  int bid = blockIdx.x;
  int mt = bid >> 2;
  int t = threadIdx.x, w = t >> 6, lane = t & 63;
  {
    int r16 = t >> 4, cg = t & 15;
    int row = mt * 16 + r16;
    int kt = cg >> 1;
    int laneLo = (cg & 1) * 32 + r16;
    int laneHi = laneLo + 16;
    const float4* hp = (const float4*)(slots_in + (size_t)row * 256 + cg * 16);
    float4 h0 = hp[0], h1 = hp[1], h2 = hp[2], h3 = hp[3];
    uint4 pk;
    pk.x = pk2(h0.x, h0.y); pk.y = pk2(h0.z, h0.w);
    pk.z = pk2(h1.x, h1.y); pk.w = pk2(h1.z, h1.w);
    *(uint4*)(hfl + (kt * 64 + laneLo) * 8) = pk;
    pk.x = pk2(h2.x, h2.y); pk.y = pk2(h2.z, h2.w);
    pk.z = pk2(h3.x, h3.y); pk.w = pk2(h3.z, h3.w);
    *(uint4*)(hfl + (kt * 64 + laneHi) * 8) = pk;
  }
  __syncthreads();
  int g = (bid & 3) * 4 + w;
  const bf16x8* wih = (const bf16x8*)wih_f;
  const bf16x8* whh = (const bf16x8*)whh_f;
  f32x4 ar = {}, az = {}, an = {}, hr = {}, hz = {}, hn = {};
#pragma unroll
  for (int kt = 0; kt < 8; ++kt) {
    bf16x8 au = *(const bf16x8*)(ufrag + ((mt * 8 + kt) * 64 + lane) * 8);
    bf16x8 ah = *(const bf16x8*)(hfl + (kt * 64 + lane) * 8);
    ar = __builtin_amdgcn_mfma_f32_16x16x32_bf16(au, wih[(g * 8 + kt) * 64 + lane], ar, 0, 0, 0);
    az = __builtin_amdgcn_mfma_f32_16x16x32_bf16(au, wih[((16 + g) * 8 + kt) * 64 + lane], az, 0, 0, 0);
    an = __builtin_amdgcn_mfma_f32_16x16x32_bf16(au, wih[((32 + g) * 8 + kt) * 64 + lane], an, 0, 0, 0);
    hr = __builtin_amdgcn_mfma_f32_16x16x32_bf16(ah, whh[(g * 8 + kt) * 64 + lane], hr, 0, 0, 0);
    hz = __builtin_amdgcn_mfma_f32_16x16x32_bf16(ah, whh[((16 + g) * 8 + kt) * 64 + lane], hz, 0, 0, 0);
    hn = __builtin_amdgcn_mfma_f32_16x16x32_bf16(ah, whh[((32 + g) * 8 + kt) * 64 + lane], hn, 0, 0, 0);
  }
  int tc = g * 16 + (lane & 15);
  float cr = bih[tc], cz = bih[256 + tc], cn = bih[512 + tc];
  float dr = bhh[tc], dz = bhh[256 + tc], dn = bhh[512 + tc];
#pragma unroll
  for (int j = 0; j < 4; ++j) {
    int row = mt * 16 + (lane >> 4) * 4 + j;
    float r = 1.f / (1.f + __expf(-(ar[j] + cr + hr[j] + dr)));
    float z = 1.f / (1.f + __expf(-(az[j] + cz + hz[j] + dz)));
    float ng = tanhf(an[j] + cn + r * (hn[j] + dn));
    float h = slots_in[row * 256 + tc];
    snew[row * 256 + tc] = (1.f - z) * ng + z * h;
  }
}

// ---------------- U2: LN(snew) inline + MLP1 -> h1 frags ----------------
__global__ __launch_bounds__(256) void k_mlp1ln(
    const float* __restrict__ sn, const float* __restrict__ gm,
    const float* __restrict__ bm, const u16* __restrict__ w1_f,
    const float* __restrict__ b1v, u16* __restrict__ h1frag) {
  __shared__ __align__(16) u16 afr[4096];
  int w = threadIdx.x >> 6, lane = threadIdx.x & 63;
  int mt = blockIdx.x >> 3;
  int d0 = lane * 4;
  float4 gvv = *(const float4*)(gm + d0);
  float4 bvv = *(const float4*)(bm + d0);
#pragma unroll
  for (int i = 0; i < 4; ++i) {
    int r16 = w * 4 + i;
    float4 v = *(const float4*)(sn + (mt * 16 + r16) * 256 + d0);
    float s = v.x + v.y + v.z + v.w;
    float ss = v.x * v.x + v.y * v.y + v.z * v.z + v.w * v.w;
#pragma unroll
    for (int o = 32; o; o >>= 1) { s += __shfl_xor(s, o); ss += __shfl_xor(ss, o); }
    float mean = s * (1.f / 256.f);
    float rstd = rsqrtf(ss * (1.f / 256.f) - mean * mean + LN_EPS);
    uint2 pk;
    pk.x = pk2((v.x - mean) * rstd * gvv.x + bvv.x, (v.y - mean) * rstd * gvv.y + bvv.y);
    pk.y = pk2((v.z - mean) * rstd * gvv.z + bvv.z, (v.w - mean) * rstd * gvv.w + bvv.w);
    int kt = lane >> 3;
    int laneA = ((lane >> 1) & 3) * 16 + r16;
    *(uint2*)(afr + (kt * 64 + laneA) * 8 + (lane & 1) * 4) = pk;
  }
  __syncthreads();
  int nt = (blockIdx.x & 7) * 4 + w;
  const bf16x8* bw = (const bf16x8*)w1_f;
  f32x4 acc = {};
#pragma unroll
  for (int kt = 0; kt < 8; ++kt)
    acc = __builtin_amdgcn_mfma_f32_16x16x32_bf16(
        *(const bf16x8*)(afr + (kt * 64 + lane) * 8),
        bw[(nt * 8 + kt) * 64 + lane], acc, 0, 0, 0);
  int col = nt * 16 + (lane & 15);
  float bbv = b1v[col];
  int kt2 = col >> 5, j2 = col & 7;
  int laneBase = ((col >> 3) & 3) * 16;
#pragma unroll
  for (int j = 0; j < 4; ++j) {
    int r = (lane >> 4) * 4 + j;
    float vv = fmaxf(acc[j] + bbv, 0.f);
    h1frag[((mt * 16 + kt2) * 64 + laneBase + r) * 8 + j2] = f2bf(vv);
  }
}

// ---------------- U3: MLP2 (h1@W2+b2) + residual -> sout ----------------
__global__ __launch_bounds__(256) void k_mlp2(
    const u16* __restrict__ h1frag, const u16* __restrict__ w2_f,
    const float* __restrict__ b2v, const float* __restrict__ snew,
    float* __restrict__ sout) {
  int w = threadIdx.x >> 6, lane = threadIdx.x & 63;
  int unit = blockIdx.x * 4 + w;       // 0..255
  int mt = unit >> 4, nt = unit & 15;
  const bf16x8* bw = (const bf16x8*)w2_f;
  f32x4 acc = {};
#pragma unroll
  for (int kt = 0; kt < 16; ++kt)
    acc = __builtin_amdgcn_mfma_f32_16x16x32_bf16(
        *(const bf16x8*)(h1frag + ((mt * 16 + kt) * 64 + lane) * 8),
        bw[(nt * 16 + kt) * 64 + lane], acc, 0, 0, 0);
  int col = nt * 16 + (lane & 15);
  float bbv = b2v[col];
#pragma unroll
  for (int j = 0; j < 4; ++j) {
    int row = mt * 16 + (lane >> 4) * 4 + j;
    sout[row * 256 + col] = acc[j] + bbv + snew[row * 256 + col];
  }
}

// ---------------- U4: LN(sout) inline + q GEMM ----------------
__global__ __launch_bounds__(256) void k_qln(
    const float* __restrict__ so, const float* __restrict__ gsv,
    const float* __restrict__ bsv, const u16* __restrict__ wq_f,
    float* __restrict__ qbuf) {
  __shared__ __align__(16) u16 afr[4096];
  int w = threadIdx.x >> 6, lane = threadIdx.x & 63;
  int mt = blockIdx.x >> 2;
  int d0 = lane * 4;
  float4 gvv = *(const float4*)(gsv + d0);
  float4 bvv = *(const float4*)(bsv + d0);
#pragma unroll
  for (int i = 0; i < 4; ++i) {
    int r16 = w * 4 + i;
    float4 v = *(const float4*)(so + (mt * 16 + r16) * 256 + d0);
    float s = v.x + v.y + v.z + v.w;
    float ss = v.x * v.x + v.y * v.y + v.z * v.z + v.w * v.w;
#pragma unroll
    for (int o = 32; o; o >>= 1) { s += __shfl_xor(s, o); ss += __shfl_xor(ss, o); }
    float mean = s * (1.f / 256.f);
    float rstd = rsqrtf(ss * (1.f / 256.f) - mean * mean + LN_EPS);
    uint2 pk;
    pk.x = pk2((v.x - mean) * rstd * gvv.x + bvv.x, (v.y - mean) * rstd * gvv.y + bvv.y);
    pk.y = pk2((v.z - mean) * rstd * gvv.z + bvv.z, (v.w - mean) * rstd * gvv.w + bvv.w);
    int kt = lane >> 3;
    int laneA = ((lane >> 1) & 3) * 16 + r16;
    *(uint2*)(afr + (kt * 64 + laneA) * 8 + (lane & 1) * 4) = pk;
  }
  __syncthreads();
  int nt = (blockIdx.x & 3) * 4 + w;
  const bf16x8* bw = (const bf16x8*)wq_f;
  f32x4 acc = {};
#pragma unroll
  for (int kt = 0; kt < 8; ++kt)
    acc = __builtin_amdgcn_mfma_f32_16x16x32_bf16(
        *(const bf16x8*)(afr + (kt * 64 + lane) * 8),
        bw[(nt * 8 + kt) * 64 + lane], acc, 0, 0, 0);
  int col = nt * 16 + (lane & 15);
#pragma unroll
  for (int j = 0; j < 4; ++j) {
    int row = mt * 16 + (lane >> 4) * 4 + j;
    qbuf[row * 256 + col] = acc[j];
  }
}

extern "C" void kernel_launch(void* const* d_in, const int* in_sizes, int n_in,
                              void* d_out, int out_size, void* d_ws, size_t ws_size,
                              hipStream_t stream) {
  (void)in_sizes; (void)n_in; (void)out_size; (void)ws_size;
  const float* inputs    = (const float*)d_in[0];
  const float* noise     = (const float*)d_in[1];
  const float* ln_in_g   = (const float*)d_in[2];
  const float* ln_in_b   = (const float*)d_in[3];
  const float* ln_slot_g = (const float*)d_in[4];
  const float* ln_slot_b = (const float*)d_in[5];
  const float* ln_mlp_g  = (const float*)d_in[6];
  const float* ln_mlp_b  = (const float*)d_in[7];
  const float* slot_mu   = (const float*)d_in[8];
  const float* slot_sig  = (const float*)d_in[9];
  const float* Wq        = (const float*)d_in[10];
  const float* Wk        = (const float*)d_in[11];
  const float* Wv        = (const float*)d_in[12];
  const float* W_ih      = (const float*)d_in[13];
  const float* W_hh      = (const float*)d_in[14];
  const float* b_ih      = (const float*)d_in[15];
  const float* b_hh      = (const float*)d_in[16];
  const float* W1        = (const float*)d_in[17];
  const float* b1        = (const float*)d_in[18];
  const float* W2        = (const float*)d_in[19];
  const float* b2        = (const float*)d_in[20];

  char* p = (char*)d_ws;
  auto take = [&](size_t bytes) { char* r = p; p += (bytes + 255) & ~(size_t)255; return r; };
  u16* xbf      = (u16*)take((size_t)131072 * 256 * 2);
  u16* kT       = (u16*)take((size_t)32 * 256 * 4096 * 2);
  u16* vT       = (u16*)take((size_t)32 * 256 * 4096 * 2);
  u16* plT      = (u16*)take((size_t)32 * 16 * 4096 * 2);
  u16* wkvT     = (u16*)take(131072 * 2);
  u16* wih_f    = (u16*)take(196608 * 2);
  u16* whh_f    = (u16*)take(196608 * 2);
  u16* w1_f     = (u16*)take(131072 * 2);
  u16* w2_f     = (u16*)take(131072 * 2);
  u16* wq_f     = (u16*)take(65536 * 2);
  u16* wqt      = (u16*)take(65536 * 2);
  u16* ufrag    = (u16*)take(65536 * 2);
  u16* h1frag   = (u16*)take(131072 * 2);
  float* snew   = (float*)take(65536 * 4);
  float* slotsA = (float*)take(256 * 256 * 4);
  float* slotsB = (float*)take(256 * 256 * 4);
  float* qbuf   = (float*)take(256 * 256 * 4);
  float* pml    = (float*)take(32 * 16 * 16 * 4);

  k_convert<<<3584, 256, 0, stream>>>(Wk, Wv, W_ih, W_hh, W1, W2, Wq,
                                      wkvT, wih_f, whh_f, w1_f, w2_f, wq_f, wqt);
  k_ln<<<32768, 256, 0, stream>>>(inputs, ln_in_g, ln_in_b, xbf);
  k_slots_init<<<256, 256, 0, stream>>>(noise, slot_mu, slot_sig, ln_slot_g, ln_slot_b, wqt, slotsA, qbuf);
  k_gemm<<<4096, 256, 0, stream>>>(xbf, wkvT, kT, vT);

  const float* scur = slotsA;
  for (int it = 0; it < 3; ++it) {
    k_dots<<<512, 256, 0, stream>>>(kT, qbuf, pml, plT);
    k_pv<<<512, 256, 0, stream>>>(plT, vT, pml, ufrag);
    k_gru2<<<64, 256, 0, stream>>>(ufrag, scur, wih_f, whh_f, b_ih, b_hh, snew);
    k_mlp1ln<<<128, 256, 0, stream>>>(snew, ln_mlp_g, ln_mlp_b, w1_f, b1, h1frag);
    float* sout = (it == 2) ? (float*)d_out : ((it == 0) ? slotsB : slotsA);
    k_mlp2<<<64, 256, 0, stream>>>(h1frag, w2_f, b2, snew, sout);
    if (it < 2) k_qln<<<64, 256, 0, stream>>>(sout, ln_slot_g, ln_slot_b, wq_f, qbuf);
    scur = sout;
  }
}